// Round 5
// baseline (229.811 us; speedup 1.0000x reference)
//
#include <hip/hip_runtime.h>
#include <math.h>

// RoPE-2D fused: R(col)*R(row) = R(row+col) (2D rotations compose additively).
// x: [B=32, S=1024, H=16, D=64] fp32. One (b,s) slice = H*D = 1024 floats = 256 float4s.
// Block = 256 threads, 8 slices (32 KB). All 8 loads issued up front (8 KB/wave
// in flight). Per-slice cols/div/i+j are wave-uniform scalar work. theta exp2
// hoisted (k depends only on tid). No LDS, no barrier (R4's __syncthreads forced
// a vmcnt(0) drain and regressed). Plain loads (m13 copy recipe), nontemporal
// stores (streaming output, skip L2).

typedef float vfloat4 __attribute__((ext_vector_type(4)));

#define CHUNKS 8

__global__ __launch_bounds__(256) void rope2d_kernel(
    const vfloat4* __restrict__ x,
    const int* __restrict__ grid_sizes,
    vfloat4* __restrict__ out)
{
    const int tid   = threadIdx.x;
    const int base4 = blockIdx.x * (256 * CHUNKS);   // first float4 of this block
    const int bs0   = blockIdx.x * CHUNKS;           // first (b*S+s) slice

    // pair index within D: k = ((tid*4) & 63) >> 1 = (tid & 15) * 2
    const int k = (tid & 15) << 1;

    const float C       = -0.41524101186092029f;  // -log2(10000)/32
    const float INV_2PI = 0.15915494309189535f;

    const float t0 = __builtin_amdgcn_exp2f((float)k * C) * INV_2PI;
    const float t1 = __builtin_amdgcn_exp2f((float)(k + 1) * C) * INV_2PI;

    // Issue all loads before any compute (8 outstanding vmem ops per lane).
    vfloat4 v[CHUNKS];
#pragma unroll
    for (int c = 0; c < CHUNKS; ++c)
        v[c] = x[base4 + c * 256 + tid];

#pragma unroll
    for (int c = 0; c < CHUNKS; ++c) {
        const int bs   = bs0 + c;                 // wave-uniform
        const int s    = bs & 1023;               // S = 1024
        const int b    = bs >> 10;
        const int cols = grid_sizes[2 * b + 1];   // uniform scalar load
        const int i    = s / cols;                // uniform scalar division
        const int j    = s - i * cols;
        const float ij = (float)(i + j);

        float r0 = ij * t0;  r0 -= floorf(r0);    // revolutions in [0,1)
        float r1 = ij * t1;  r1 -= floorf(r1);

        const float s0 = __builtin_amdgcn_sinf(r0);
        const float c0 = __builtin_amdgcn_cosf(r0);
        const float s1 = __builtin_amdgcn_sinf(r1);
        const float c1 = __builtin_amdgcn_cosf(r1);

        vfloat4 o;
        o.x = v[c].x * c0 - v[c].y * s0;
        o.y = v[c].y * c0 + v[c].x * s0;
        o.z = v[c].z * c1 - v[c].w * s1;
        o.w = v[c].w * c1 + v[c].z * s1;
        __builtin_nontemporal_store(o, &out[base4 + c * 256 + tid]);
    }
}

extern "C" void kernel_launch(void* const* d_in, const int* in_sizes, int n_in,
                              void* d_out, int out_size, void* d_ws, size_t ws_size,
                              hipStream_t stream) {
    const vfloat4* x  = (const vfloat4*)d_in[0];
    const int*     gs = (const int*)d_in[1];
    vfloat4*       o  = (vfloat4*)d_out;

    const int n4     = in_sizes[0] >> 2;        // 8,388,608 float4s
    const int blocks = n4 / (256 * CHUNKS);     // 4096 blocks, exact coverage

    rope2d_kernel<<<blocks, 256, 0, stream>>>(x, gs, o);
}